// Round 16
// baseline (1663.950 us; speedup 1.0000x reference)
//
#include <hip/hip_runtime.h>
#include <hip/hip_bf16.h>

typedef __hip_bfloat16 bf16;
typedef unsigned short u16x8 __attribute__((ext_vector_type(8)));
using v8s = __attribute__((ext_vector_type(8))) short;   // bf16 x8 MFMA frag (4 VGPR)
using v4f = __attribute__((ext_vector_type(4))) float;   // f32 x4 acc frag

#define L_SEQ 2048
#define BATCH 8
#define NIN   1024    // 2H
#define WLD   3072    // W row stride, layers 1-3
#define NHALF 1536    // per-direction columns (3*H)
#define NROWS (L_SEQ*BATCH)

__device__ __forceinline__ float bits2f(unsigned short u){ return __uint_as_float(((unsigned)u)<<16); }
__device__ __forceinline__ float b2f(bf16 v){ return __bfloat162float(v); }
__device__ __forceinline__ bf16  f2b(float v){ return __float2bfloat16(v); }
__device__ __forceinline__ float sigm(float z){ return __fdividef(1.0f, 1.0f + __expf(-z)); }

__device__ __forceinline__ void gload16(const void* g, void* l){
    __builtin_amdgcn_global_load_lds((const __attribute__((address_space(1))) void*)g,
                                     (__attribute__((address_space(3))) void*)l, 16, 0, 0);
}

__global__ void k_code(float* __restrict__ out, float v){
    if (threadIdx.x == 0 && blockIdx.x == 0) out[0] = v;
}

// ---------------- dxT[b][l] = X[b][l] - X[b][l-1], 0 at l=0  ((B,L) layout)
__global__ __launch_bounds__(256) void k_diff(const float* __restrict__ X, float* __restrict__ dxT){
    int i = blockIdx.x*256 + threadIdx.x;
    if (i >= NROWS) return;
    int l = i & (L_SEQ-1);
    float v = 0.f;
    if (l > 0) v = X[i] - X[i-1];
    dxT[i] = v;
}

// ---------------- W (fp32 [1024][3072]) -> Wt (bf16 [3072][1024], transposed)
__global__ __launch_bounds__(256) void k_wt(const float* __restrict__ W, bf16* __restrict__ Wt){
    __shared__ float t[32][33];
    int k0 = blockIdx.x*32, n0 = blockIdx.y*32;
    int tx = threadIdx.x & 31, ty = threadIdx.x >> 5;   // ty 0..7
    #pragma unroll
    for (int j=0;j<4;j++)
        t[ty*4+j][tx] = W[(size_t)(k0+ty*4+j)*WLD + n0 + tx];
    __syncthreads();
    #pragma unroll
    for (int j=0;j<4;j++)
        Wt[(size_t)(n0+ty*4+j)*NIN + k0 + tx] = f2b(t[tx][ty*4+j]);
}

// ---------------- layer 0 (round-14 hoisted version, 201us measured)
__global__ __launch_bounds__(256) void k_layer0(const float* __restrict__ dxT, const float* __restrict__ W0,
                                                const float* __restrict__ wc, const float* __restrict__ bb,
                                                bf16* __restrict__ xout){
    __shared__ float sdx[L_SEQ];
    int g = blockIdx.x*256 + threadIdx.x;           // 8192 threads: (d,b,h); b,d block-uniform
    int h = g & 511, b = (g>>9) & 7, d = g >> 12;
    const float* dxp = dxT + b*L_SEQ;
    for (int t = threadIdx.x; t < L_SEQ; t += 256) sdx[t] = dxp[t];
    __syncthreads();

    int dcol = d*512 + h;
    float w0 = W0[d*2048 + h];
    float w1 = W0[d*2048 + 512 + h];
    float w2 = W0[d*2048 + 1024 + h];
    float w3 = W0[d*2048 + 1536 + h];
    float vf = wc[dcol],  vr = wc[1024 + dcol];
    float bfv = bb[dcol], brv = bb[1024 + dcol];
    float c = 0.f;

    int t0 = d ? (L_SEQ-1) : 0;
    bf16* xq = xout + ((size_t)t0*BATCH + b)*NIN + dcol;
    ptrdiff_t xs = d ? -(ptrdiff_t)(BATCH*NIN) : (ptrdiff_t)(BATCH*NIN);

#define LD0(P0,P1,P2,P3, s0) do{                                     \
        _Pragma("unroll")                                            \
        for (int i_=0;i_<8;i_++){                                    \
            int ss_ = (s0)+i_;                                       \
            float xv_ = sdx[d ? (L_SEQ-1-ss_) : ss_];                \
            P0[i_] = xv_*w0;                                         \
            P1[i_] = xv_*w1 + bfv;                                   \
            P2[i_] = xv_*w2 + brv;                                   \
            P3[i_] = xv_*w3;                                         \
        }                                                            \
        __builtin_amdgcn_sched_barrier(0);                           \
    }while(0)

#define STEP0(p0,p1,p2,p3) do{                                       \
        float f_ = sigm((p1) + vf*c);                                \
        c = (p0) + f_*(c - (p0));                                    \
        float r_ = sigm((p2) + vr*c);                                \
        float hv_ = (p3) + r_*(c - (p3));                            \
        *xq = f2b(hv_);  xq += xs;                                   \
    }while(0)

    float A0[8],A1[8],A2[8],A3[8], B0[8],B1[8],B2[8],B3[8];
    LD0(A0,A1,A2,A3, 0);
    for (int s0 = 0; s0 + 32 <= L_SEQ; s0 += 16){
        LD0(B0,B1,B2,B3, s0+8);
        #pragma unroll
        for (int i=0;i<8;i++) STEP0(A0[i],A1[i],A2[i],A3[i]);
        LD0(A0,A1,A2,A3, s0+16);
        #pragma unroll
        for (int i=0;i<8;i++) STEP0(B0[i],B1[i],B2[i],B3[i]);
    }
    LD0(B0,B1,B2,B3, L_SEQ-8);
    #pragma unroll
    for (int i=0;i<8;i++) STEP0(A0[i],A1[i],A2[i],A3[i]);
    #pragma unroll
    for (int i=0;i<8;i++) STEP0(B0[i],B1[i],B2[i],B3[i]);
#undef LD0
#undef STEP0
}

// ---------------- MFMA GEMM: UcH[set s] = x[all rows] @ Wt[set s]^T   (bf16 output)
// 128x128 tile, BK=32, 4 waves, triple-buffer dist-2, swizzle retained.
__global__ __launch_bounds__(256) void k_gemm(const bf16* __restrict__ Xin, const bf16* __restrict__ Wt,
                                              bf16* __restrict__ Uc, int l0, int C){
    __shared__ bf16 As[3][4096];   // [buf][128 m][32 k], 64B rows (8KB/buf)
    __shared__ bf16 Bs[3][4096];
    int tid = threadIdx.x;
    int lane = tid & 63;
    int s = blockIdx.z;
    int base = (s == 0) ? l0 : (L_SEQ - l0 - C);
    const bf16* A  = Xin + (size_t)base*BATCH*NIN;
    const bf16* Bm = Wt + (size_t)s*NHALF*NIN;
    bf16*       Cc = Uc + (size_t)s*(size_t)C*BATCH*NHALF;

    int m0 = blockIdx.x*128, n0 = blockIdx.y*128;
    int wv = tid >> 6;
    int wm = (wv >> 1)*64, wn = (wv & 1)*64;

    v4f acc[4][4];
    #pragma unroll
    for (int i=0;i<4;i++)
        #pragma unroll
        for (int j=0;j<4;j++)
            #pragma unroll
            for (int r=0;r<4;r++) acc[i][j][r] = 0.f;

    int row_a = tid >> 2;
    int kb = (((tid & 3) ^ ((tid >> 3) & 3)))*8;            // source-side swizzle
    int wbase = (tid & 192)*16;
    int fro = (lane & 15)*64 + (((lane >> 4) ^ (((lane & 15) >> 1) & 3)))*16;  // read-side swizzle

#define STAGE(q, k0) do{                                                        \
        char* la_ = (char*)As[0] + (q)*8192;                                    \
        char* lb_ = (char*)Bs[0] + (q)*8192;                                    \
        gload16(A  + (size_t)(m0 + row_a      )*NIN + (k0) + kb, la_ + wbase);  \
        gload16(A  + (size_t)(m0 + row_a + 64 )*NIN + (k0) + kb, la_ + 4096 + wbase); \
        gload16(Bm + (size_t)(n0 + row_a      )*NIN + (k0) + kb, lb_ + wbase);  \
        gload16(Bm + (size_t)(n0 + row_a + 64 )*NIN + (k0) + kb, lb_ + 4096 + wbase); \
    }while(0)

    STAGE(0, 0);
    STAGE(1, 32);
    int cur = 0;
    for (int it = 0; it < 32; ++it){
        if (it < 30){
            int nb = cur + 2; if (nb >= 3) nb -= 3;
            STAGE(nb, (it+2)*32);
            asm volatile("s_waitcnt vmcnt(8)" ::: "memory");   // drain tile-it (2 iters old)
        } else if (it == 30){
            asm volatile("s_waitcnt vmcnt(4)" ::: "memory");
        } else {
            asm volatile("s_waitcnt vmcnt(0)" ::: "memory");
        }
        __builtin_amdgcn_sched_barrier(0);
        __builtin_amdgcn_s_barrier();
        const char* la = (const char*)As[0] + cur*8192;
        const char* lb = (const char*)Bs[0] + cur*8192;
        v8s av[4], bv[4];
        #pragma unroll
        for (int i=0;i<4;i++) av[i] = *(const v8s*)(la + (wm + i*16)*64 + fro);
        #pragma unroll
        for (int j=0;j<4;j++) bv[j] = *(const v8s*)(lb + (wn + j*16)*64 + fro);
        #pragma unroll
        for (int i=0;i<4;i++)
            #pragma unroll
            for (int j=0;j<4;j++)
                acc[i][j] = __builtin_amdgcn_mfma_f32_16x16x32_bf16(av[i], bv[j], acc[i][j], 0, 0, 0);
        __builtin_amdgcn_s_barrier();
        cur = cur + 1; if (cur == 3) cur = 0;
    }
#undef STAGE

    int cr = (lane >> 4)*4, ccol = lane & 15;
    #pragma unroll
    for (int i=0;i<4;i++){
        #pragma unroll
        for (int j=0;j<4;j++){
            size_t rb = (size_t)(m0 + wm + i*16 + cr)*NHALF + (n0 + wn + j*16 + ccol);
            #pragma unroll
            for (int r=0;r<4;r++) Cc[rb + (size_t)r*NHALF] = f2b(acc[i][j][r]);
        }
    }
}

// ---------------- recurrence, layers 1-3: LDS-staged bf16 U + x via global_load_lds.
// FIX (round 16): vmcnt(12), not (4) — at the wait, queue = [loads(g)=4 | stores(g-1)=8 |
// loads(g+1)=4]; vmcnt(12) drains exactly loads(g) and leaves the 8 dead-in-kernel output
// stores in flight. vmcnt(4) was forcing store-completion every group (~2300cy/group stall).
__global__ __launch_bounds__(256) void k_rec(const bf16* __restrict__ Uc, const bf16* __restrict__ xin,
                                             bf16* __restrict__ xout, float* __restrict__ carry,
                                             const float* __restrict__ wc, const float* __restrict__ bb,
                                             int l0, int C){
    __shared__ bf16 Ub[2][6144];    // [buf][seg=step*3+gate][256 bf16]  2x12KB
    __shared__ bf16 Xb[2][2048];    // [buf][step][256 bf16]             2x4KB
    int tid = threadIdx.x;
    int lane = tid & 63, wv = tid >> 6;
    int bid = blockIdx.x;
    int d = bid >> 4, b = (bid >> 1) & 7, hbase = (bid & 1)*256;
    int h = hbase + tid;
    int dcol = d*512 + h;
    int ch = d*4096 + b*512 + h;
    float vf = wc[d*512 + h], vr = wc[1024 + d*512 + h];
    float bfv = bb[d*512 + h], brv = bb[1024 + d*512 + h];
    float c = (l0 == 0) ? 0.f : carry[ch];

    const bf16* Ubase = Uc + (size_t)d*(size_t)C*12288 + b*1536 + hbase;   // row stride 12288 bf16

#define RSTAGE(base_, q_) do{                                                   \
        char* ub_ = (char*)Ub[q_]; char* xb_ = (char*)Xb[q_];                   \
        _Pragma("unroll")                                                       \
        for (int qq=0; qq<3; ++qq){                                             \
            int seg = qq*8 + wv*2 + (lane>>5);      /* per-lane seg 0..23 */    \
            int st_ = seg/3, gate_ = seg - st_*3;                               \
            int ss_ = (base_) + st_;                                            \
            int row_ = d ? (C-1-ss_) : ss_;                                     \
            gload16(Ubase + (size_t)row_*12288 + gate_*512 + (lane&31)*8,       \
                    ub_ + (qq*8 + wv*2)*512);                                   \
        }                                                                       \
        {   int st_ = (base_) + 2*wv + (lane>>5);                               \
            int t_  = d ? (L_SEQ-1 - l0 - st_) : (l0 + st_);                    \
            gload16(xin + ((size_t)t_*BATCH + b)*NIN + d*512 + hbase + (lane&31)*8, \
                    xb_ + wv*1024);                                             \
        }                                                                       \
    }while(0)

#define RCOMP(base_, q_) do{                                                    \
        float u0[8],u1[8],u2[8],xr[8];                                          \
        _Pragma("unroll")                                                       \
        for (int i_=0;i_<8;i_++){                                               \
            u0[i_]=b2f(Ub[q_][(i_*3+0)*256+tid]); u1[i_]=b2f(Ub[q_][(i_*3+1)*256+tid]); \
            u2[i_]=b2f(Ub[q_][(i_*3+2)*256+tid]); xr[i_]=b2f(Xb[q_][i_*256+tid]);       \
        }                                                                       \
        __builtin_amdgcn_sched_barrier(0);                                      \
        _Pragma("unroll")                                                       \
        for (int i_=0;i_<8;i_++){                                               \
            int ss_=(base_)+i_;                                                 \
            int t_ = d ? (L_SEQ-1-l0-ss_) : (l0+ss_);                           \
            float f_=sigm(u1[i_] + vf*c + bfv);                                 \
            c = f_*c + (1.f-f_)*u0[i_];                                         \
            float r_=sigm(u2[i_] + vr*c + brv);                                 \
            xout[((size_t)t_*BATCH + b)*NIN + dcol] = f2b(r_*c + (1.f-r_)*xr[i_]); \
        }                                                                       \
    }while(0)

    RSTAGE(0, 0);
    asm volatile("s_waitcnt vmcnt(0)" ::: "memory");
    __builtin_amdgcn_sched_barrier(0);
    __builtin_amdgcn_s_barrier();
    int ngrp = C >> 3;
    for (int g = 0; g < ngrp; ++g){
        int q = g & 1;
        if (g + 1 < ngrp){
            RSTAGE((g+1)*8, q^1);                            // queue: L(g)4 | S(g-1)8 | L(g+1)4
            asm volatile("s_waitcnt vmcnt(12)" ::: "memory");// drain exactly L(g); stores stay in flight
        } else {
            asm volatile("s_waitcnt vmcnt(8)" ::: "memory"); // queue: L(g)4 | S(g-1)8 -> drain L(g)
        }
        __builtin_amdgcn_sched_barrier(0);
        __builtin_amdgcn_s_barrier();
        RCOMP(g*8, q);
        __builtin_amdgcn_s_barrier();
    }
    carry[ch] = c;
#undef RSTAGE
#undef RCOMP
}

// ---------------- classifier: out[(b*L + l)*3 + j] = h[row l*8+b] @ Wcls + bcls
__global__ __launch_bounds__(256) void k_cls(const bf16* __restrict__ Xf, const float* __restrict__ Wc,
                                             const float* __restrict__ bc, float* __restrict__ out){
    int wave = threadIdx.x >> 6, lane = threadIdx.x & 63;
    int row = blockIdx.x*4 + wave;                  // row = l*8+b
    const bf16* xp = Xf + (size_t)row*NIN + lane*16;
    u16x8 v0 = *(const u16x8*)(xp);
    u16x8 v1 = *(const u16x8*)(xp + 8);
    float a0=0.f, a1=0.f, a2=0.f;
    #pragma unroll
    for (int i=0;i<16;i++){
        float xv = bits2f(i<8 ? v0[i&7] : v1[i&7]);
        int k = lane*16 + i;
        a0 += xv*Wc[k*3+0];
        a1 += xv*Wc[k*3+1];
        a2 += xv*Wc[k*3+2];
    }
    #pragma unroll
    for (int off=32; off; off>>=1){
        a0 += __shfl_down(a0, off);
        a1 += __shfl_down(a1, off);
        a2 += __shfl_down(a2, off);
    }
    if (lane == 0){
        int l = row >> 3, b = row & 7;
        float* op = out + ((size_t)b*L_SEQ + l)*3;
        op[0] = a0 + bc[0];
        op[1] = a1 + bc[1];
        op[2] = a2 + bc[2];
    }
}

// ----------------------------------------------------------------
extern "C" void kernel_launch(void* const* d_in, const int* in_sizes, int n_in,
                              void* d_out, int out_size, void* d_ws, size_t ws_size,
                              hipStream_t stream){
    (void)in_sizes; (void)n_in; (void)out_size;
    const float* X    = (const float*)d_in[0];
    const float* W[4]  = {(const float*)d_in[1],(const float*)d_in[4],(const float*)d_in[7],(const float*)d_in[10]};
    const float* wc[4] = {(const float*)d_in[2],(const float*)d_in[5],(const float*)d_in[8],(const float*)d_in[11]};
    const float* bb[4] = {(const float*)d_in[3],(const float*)d_in[6],(const float*)d_in[9],(const float*)d_in[12]};
    const float* Wcls = (const float*)d_in[13];
    const float* bcls = (const float*)d_in[14];
    float* out = (float*)d_out;

    // workspace layout:
    //   xA    bf16[16384*1024]  @ 0           33,554,432
    //   xB    bf16[16384*1024]  @ 33554432    33,554,432
    //   dxT   f32 [8*2048]      @ 67108864        65,536
    //   carry f32 [8192]        @ 67174400        32,768
    //   Wt0-2 bf16[3072*1024]   @ 67207168    3 x 6,291,456
    //   Ucb   bf16[C*2*8*1536]  @ 86081536    C*49,152   (C=2048 -> 100MB)
    char*  ws    = (char*)d_ws;
    bf16*  xA    = (bf16*)ws;
    bf16*  xB    = (bf16*)(ws + 33554432);
    float* dxT   = (float*)(ws + 67108864);
    float* carry = (float*)(ws + 67174400);
    bf16*  Wt[3] = {(bf16*)(ws + 67207168), (bf16*)(ws + 73498624), (bf16*)(ws + 79790080)};
    bf16*  Ucb   = (bf16*)(ws + 86081536);
    const size_t NEEDED = 86081536ull + 64ull*49152ull;

    if (ws_size < NEEDED){
        float code = 1.0e6f + (float)((ws_size >> 20) > 9999 ? 9999 : (ws_size >> 20)) * 100.0f;
        k_code<<<1, 64, 0, stream>>>(out, code);
        return;
    }

    int C = 2048;
    while (C > 64 && 86081536ull + (size_t)C*49152ull > ws_size) C >>= 1;

    k_diff  <<<(NROWS+255)/256, 256, 0, stream>>>(X, dxT);
    for (int i = 0; i < 3; ++i)
        k_wt<<<dim3(32,96), 256, 0, stream>>>(W[i+1], Wt[i]);
    k_layer0<<<32, 256, 0, stream>>>(dxT, W[0], wc[0], bb[0], xA);

    bf16* xin = xA; bf16* xo = xB;
    for (int layer = 1; layer < 4; ++layer){
        for (int l0 = 0; l0 < L_SEQ; l0 += C){
            dim3 g(C*8/128, NHALF/128, 2);
            k_gemm<<<g, 256, 0, stream>>>(xin, Wt[layer-1], Ucb, l0, C);
            k_rec <<<32, 256, 0, stream>>>(Ucb, xin, xo, carry, wc[layer], bb[layer], l0, C);
        }
        bf16* t = xin; xin = xo; xo = t;
    }
    k_cls<<<NROWS/4, 256, 0, stream>>>(xin, Wcls, bcls, out);
}

// Round 18
// 1513.906 us; speedup vs baseline: 1.0991x; 1.0991x over previous
//
#include <hip/hip_runtime.h>
#include <hip/hip_bf16.h>

typedef __hip_bfloat16 bf16;
typedef unsigned short u16x8 __attribute__((ext_vector_type(8)));
using v8s = __attribute__((ext_vector_type(8))) short;   // bf16 x8 MFMA frag (4 VGPR)
using v4f = __attribute__((ext_vector_type(4))) float;   // f32 x4 acc frag

#define L_SEQ 2048
#define BATCH 8
#define NIN   1024    // 2H
#define WLD   3072    // W row stride, layers 1-3
#define NHALF 1536    // per-direction columns (3*H)
#define NROWS (L_SEQ*BATCH)

__device__ __forceinline__ float bits2f(unsigned short u){ return __uint_as_float(((unsigned)u)<<16); }
__device__ __forceinline__ float b2f(bf16 v){ return __bfloat162float(v); }
__device__ __forceinline__ bf16  f2b(float v){ return __float2bfloat16(v); }
__device__ __forceinline__ float sigm(float z){ return __fdividef(1.0f, 1.0f + __expf(-z)); }

__device__ __forceinline__ void gload16(const void* g, void* l){
    __builtin_amdgcn_global_load_lds((const __attribute__((address_space(1))) void*)g,
                                     (__attribute__((address_space(3))) void*)l, 16, 0, 0);
}

__global__ void k_code(float* __restrict__ out, float v){
    if (threadIdx.x == 0 && blockIdx.x == 0) out[0] = v;
}

// ---------------- dxT[b][l] = X[b][l] - X[b][l-1], 0 at l=0  ((B,L) layout)
__global__ __launch_bounds__(256) void k_diff(const float* __restrict__ X, float* __restrict__ dxT){
    int i = blockIdx.x*256 + threadIdx.x;
    if (i >= NROWS) return;
    int l = i & (L_SEQ-1);
    float v = 0.f;
    if (l > 0) v = X[i] - X[i-1];
    dxT[i] = v;
}

// ---------------- W (fp32 [1024][3072]) -> Wt (bf16 [3072][1024], transposed)
__global__ __launch_bounds__(256) void k_wt(const float* __restrict__ W, bf16* __restrict__ Wt){
    __shared__ float t[32][33];
    int k0 = blockIdx.x*32, n0 = blockIdx.y*32;
    int tx = threadIdx.x & 31, ty = threadIdx.x >> 5;   // ty 0..7
    #pragma unroll
    for (int j=0;j<4;j++)
        t[ty*4+j][tx] = W[(size_t)(k0+ty*4+j)*WLD + n0 + tx];
    __syncthreads();
    #pragma unroll
    for (int j=0;j<4;j++)
        Wt[(size_t)(n0+ty*4+j)*NIN + k0 + tx] = f2b(t[tx][ty*4+j]);
}

// ---------------- layer 0 (round-14 hoisted version, 201us measured)
__global__ __launch_bounds__(256) void k_layer0(const float* __restrict__ dxT, const float* __restrict__ W0,
                                                const float* __restrict__ wc, const float* __restrict__ bb,
                                                bf16* __restrict__ xout){
    __shared__ float sdx[L_SEQ];
    int g = blockIdx.x*256 + threadIdx.x;           // 8192 threads: (d,b,h); b,d block-uniform
    int h = g & 511, b = (g>>9) & 7, d = g >> 12;
    const float* dxp = dxT + b*L_SEQ;
    for (int t = threadIdx.x; t < L_SEQ; t += 256) sdx[t] = dxp[t];
    __syncthreads();

    int dcol = d*512 + h;
    float w0 = W0[d*2048 + h];
    float w1 = W0[d*2048 + 512 + h];
    float w2 = W0[d*2048 + 1024 + h];
    float w3 = W0[d*2048 + 1536 + h];
    float vf = wc[dcol],  vr = wc[1024 + dcol];
    float bfv = bb[dcol], brv = bb[1024 + dcol];
    float c = 0.f;

    int t0 = d ? (L_SEQ-1) : 0;
    bf16* xq = xout + ((size_t)t0*BATCH + b)*NIN + dcol;
    ptrdiff_t xs = d ? -(ptrdiff_t)(BATCH*NIN) : (ptrdiff_t)(BATCH*NIN);

#define LD0(P0,P1,P2,P3, s0) do{                                     \
        _Pragma("unroll")                                            \
        for (int i_=0;i_<8;i_++){                                    \
            int ss_ = (s0)+i_;                                       \
            float xv_ = sdx[d ? (L_SEQ-1-ss_) : ss_];                \
            P0[i_] = xv_*w0;                                         \
            P1[i_] = xv_*w1 + bfv;                                   \
            P2[i_] = xv_*w2 + brv;                                   \
            P3[i_] = xv_*w3;                                         \
        }                                                            \
        __builtin_amdgcn_sched_barrier(0);                           \
    }while(0)

#define STEP0(p0,p1,p2,p3) do{                                       \
        float f_ = sigm((p1) + vf*c);                                \
        c = (p0) + f_*(c - (p0));                                    \
        float r_ = sigm((p2) + vr*c);                                \
        float hv_ = (p3) + r_*(c - (p3));                            \
        *xq = f2b(hv_);  xq += xs;                                   \
    }while(0)

    float A0[8],A1[8],A2[8],A3[8], B0[8],B1[8],B2[8],B3[8];
    LD0(A0,A1,A2,A3, 0);
    for (int s0 = 0; s0 + 32 <= L_SEQ; s0 += 16){
        LD0(B0,B1,B2,B3, s0+8);
        #pragma unroll
        for (int i=0;i<8;i++) STEP0(A0[i],A1[i],A2[i],A3[i]);
        LD0(A0,A1,A2,A3, s0+16);
        #pragma unroll
        for (int i=0;i<8;i++) STEP0(B0[i],B1[i],B2[i],B3[i]);
    }
    LD0(B0,B1,B2,B3, L_SEQ-8);
    #pragma unroll
    for (int i=0;i<8;i++) STEP0(A0[i],A1[i],A2[i],A3[i]);
    #pragma unroll
    for (int i=0;i<8;i++) STEP0(B0[i],B1[i],B2[i],B3[i]);
#undef LD0
#undef STEP0
}

// ---------------- MFMA GEMM: UcH[set s] = x[all rows] @ Wt[set s]^T   (bf16 output)
// 128x128 tile, BK=32, 4 waves, triple-buffer dist-2, swizzle retained. (unchanged)
__global__ __launch_bounds__(256) void k_gemm(const bf16* __restrict__ Xin, const bf16* __restrict__ Wt,
                                              bf16* __restrict__ Uc, int l0, int C){
    __shared__ bf16 As[3][4096];   // [buf][128 m][32 k], 64B rows (8KB/buf)
    __shared__ bf16 Bs[3][4096];
    int tid = threadIdx.x;
    int lane = tid & 63;
    int s = blockIdx.z;
    int base = (s == 0) ? l0 : (L_SEQ - l0 - C);
    const bf16* A  = Xin + (size_t)base*BATCH*NIN;
    const bf16* Bm = Wt + (size_t)s*NHALF*NIN;
    bf16*       Cc = Uc + (size_t)s*(size_t)C*BATCH*NHALF;

    int m0 = blockIdx.x*128, n0 = blockIdx.y*128;
    int wv = tid >> 6;
    int wm = (wv >> 1)*64, wn = (wv & 1)*64;

    v4f acc[4][4];
    #pragma unroll
    for (int i=0;i<4;i++)
        #pragma unroll
        for (int j=0;j<4;j++)
            #pragma unroll
            for (int r=0;r<4;r++) acc[i][j][r] = 0.f;

    int row_a = tid >> 2;
    int kb = (((tid & 3) ^ ((tid >> 3) & 3)))*8;            // source-side swizzle
    int wbase = (tid & 192)*16;
    int fro = (lane & 15)*64 + (((lane >> 4) ^ (((lane & 15) >> 1) & 3)))*16;  // read-side swizzle

#define STAGE(q, k0) do{                                                        \
        char* la_ = (char*)As[0] + (q)*8192;                                    \
        char* lb_ = (char*)Bs[0] + (q)*8192;                                    \
        gload16(A  + (size_t)(m0 + row_a      )*NIN + (k0) + kb, la_ + wbase);  \
        gload16(A  + (size_t)(m0 + row_a + 64 )*NIN + (k0) + kb, la_ + 4096 + wbase); \
        gload16(Bm + (size_t)(n0 + row_a      )*NIN + (k0) + kb, lb_ + wbase);  \
        gload16(Bm + (size_t)(n0 + row_a + 64 )*NIN + (k0) + kb, lb_ + 4096 + wbase); \
    }while(0)

    STAGE(0, 0);
    STAGE(1, 32);
    int cur = 0;
    for (int it = 0; it < 32; ++it){
        if (it < 30){
            int nb = cur + 2; if (nb >= 3) nb -= 3;
            STAGE(nb, (it+2)*32);
            asm volatile("s_waitcnt vmcnt(8)" ::: "memory");   // drain tile-it (2 iters old)
        } else if (it == 30){
            asm volatile("s_waitcnt vmcnt(4)" ::: "memory");
        } else {
            asm volatile("s_waitcnt vmcnt(0)" ::: "memory");
        }
        __builtin_amdgcn_sched_barrier(0);
        __builtin_amdgcn_s_barrier();
        const char* la = (const char*)As[0] + cur*8192;
        const char* lb = (const char*)Bs[0] + cur*8192;
        v8s av[4], bv[4];
        #pragma unroll
        for (int i=0;i<4;i++) av[i] = *(const v8s*)(la + (wm + i*16)*64 + fro);
        #pragma unroll
        for (int j=0;j<4;j++) bv[j] = *(const v8s*)(lb + (wn + j*16)*64 + fro);
        #pragma unroll
        for (int i=0;i<4;i++)
            #pragma unroll
            for (int j=0;j<4;j++)
                acc[i][j] = __builtin_amdgcn_mfma_f32_16x16x32_bf16(av[i], bv[j], acc[i][j], 0, 0, 0);
        __builtin_amdgcn_s_barrier();
        cur = cur + 1; if (cur == 3) cur = 0;
    }
#undef STAGE

    int cr = (lane >> 4)*4, ccol = lane & 15;
    #pragma unroll
    for (int i=0;i<4;i++){
        #pragma unroll
        for (int j=0;j<4;j++){
            size_t rb = (size_t)(m0 + wm + i*16 + cr)*NHALF + (n0 + wn + j*16 + ccol);
            #pragma unroll
            for (int r=0;r<4;r++) Cc[rb + (size_t)r*NHALF] = f2b(acc[i][j][r]);
        }
    }
}

// ---------------- recurrence, layers 1-3: 16-STEP groups (halved group count, doubled
// prefetch cover, halved barrier count). LDS 64KB: 2 bufs x (24KB U + 8KB x).
// vmcnt exact: steady wait = S(g-1)16 + L(g+1)8 younger than L(g) -> vmcnt(24); tail vmcnt(16).
__global__ __launch_bounds__(256) void k_rec(const bf16* __restrict__ Uc, const bf16* __restrict__ xin,
                                             bf16* __restrict__ xout, float* __restrict__ carry,
                                             const float* __restrict__ wc, const float* __restrict__ bb,
                                             int l0, int C){
    __shared__ bf16 Ub[2][12288];   // [buf][seg=step*3+gate][256 bf16]  2x24KB
    __shared__ bf16 Xb[2][4096];    // [buf][step][256 bf16]             2x8KB
    int tid = threadIdx.x;
    int lane = tid & 63, wv = tid >> 6;
    int bid = blockIdx.x;
    int d = bid >> 4, b = (bid >> 1) & 7, hbase = (bid & 1)*256;
    int h = hbase + tid;
    int dcol = d*512 + h;
    int ch = d*4096 + b*512 + h;
    float vf = wc[d*512 + h], vr = wc[1024 + d*512 + h];
    float bfv = bb[d*512 + h], brv = bb[1024 + d*512 + h];
    float c = (l0 == 0) ? 0.f : carry[ch];

    const bf16* Ubase = Uc + (size_t)d*(size_t)C*12288 + b*1536 + hbase;   // row stride 12288 bf16

    // 16 steps/group: 48 U-segs (6 gloads/wave, 2 segs each) + 16 x-rows (2 gloads/wave)
#define RSTAGE(base_, q_) do{                                                   \
        char* ub_ = (char*)Ub[q_]; char* xb_ = (char*)Xb[q_];                   \
        _Pragma("unroll")                                                       \
        for (int qq=0; qq<6; ++qq){                                             \
            int seg = qq*8 + wv*2 + (lane>>5);      /* 0..47, each once */      \
            int st_ = seg/3, gate_ = seg - st_*3;                               \
            int ss_ = (base_) + st_;                                            \
            int row_ = d ? (C-1-ss_) : ss_;                                     \
            gload16(Ubase + (size_t)row_*12288 + gate_*512 + (lane&31)*8,       \
                    ub_ + (qq*8 + wv*2)*512);                                   \
        }                                                                       \
        _Pragma("unroll")                                                       \
        for (int j=0;j<2;++j){                                                  \
            int st_ = (base_) + j*8 + wv*2 + (lane>>5);                         \
            int t_  = d ? (L_SEQ-1 - l0 - st_) : (l0 + st_);                    \
            gload16(xin + ((size_t)t_*BATCH + b)*NIN + d*512 + hbase + (lane&31)*8, \
                    xb_ + (j*8 + wv*2)*512);                                    \
        }                                                                       \
    }while(0)

#define RCOMP(base_, q_) do{                                                    \
        float u0[16],u1[16],u2[16],xr[16];                                      \
        _Pragma("unroll")                                                       \
        for (int i_=0;i_<16;i_++){                                              \
            u0[i_]=b2f(Ub[q_][(i_*3+0)*256+tid]);                               \
            u1[i_]=b2f(Ub[q_][(i_*3+1)*256+tid]) + bfv;                         \
            u2[i_]=b2f(Ub[q_][(i_*3+2)*256+tid]) + brv;                         \
            xr[i_]=b2f(Xb[q_][i_*256+tid]);                                     \
        }                                                                       \
        __builtin_amdgcn_sched_barrier(0);                                      \
        _Pragma("unroll")                                                       \
        for (int i_=0;i_<16;i_++){                                              \
            int ss_=(base_)+i_;                                                 \
            int t_ = d ? (L_SEQ-1-l0-ss_) : (l0+ss_);                           \
            float f_=sigm(u1[i_] + vf*c);                                       \
            c = u0[i_] + f_*(c - u0[i_]);                                       \
            float r_=sigm(u2[i_] + vr*c);                                       \
            xout[((size_t)t_*BATCH + b)*NIN + dcol] = f2b(xr[i_] + r_*(c - xr[i_])); \
        }                                                                       \
    }while(0)

    RSTAGE(0, 0);
    asm volatile("s_waitcnt vmcnt(0)" ::: "memory");
    __builtin_amdgcn_sched_barrier(0);
    __builtin_amdgcn_s_barrier();
    int ngrp = C >> 4;
    for (int g = 0; g < ngrp; ++g){
        int q = g & 1;
        if (g + 1 < ngrp){
            RSTAGE((g+1)*16, q^1);                           // queue: L(g)8 | S(g-1)16 | L(g+1)8
            asm volatile("s_waitcnt vmcnt(24)" ::: "memory");// drain exactly L(g)
        } else {
            asm volatile("s_waitcnt vmcnt(16)" ::: "memory");// queue: L(g)8 | S(g-1)16
        }
        __builtin_amdgcn_sched_barrier(0);
        __builtin_amdgcn_s_barrier();
        RCOMP(g*16, q);
        __builtin_amdgcn_s_barrier();
    }
    carry[ch] = c;
#undef RSTAGE
#undef RCOMP
}

// ---------------- classifier: out[(b*L + l)*3 + j] = h[row l*8+b] @ Wcls + bcls
__global__ __launch_bounds__(256) void k_cls(const bf16* __restrict__ Xf, const float* __restrict__ Wc,
                                             const float* __restrict__ bc, float* __restrict__ out){
    int wave = threadIdx.x >> 6, lane = threadIdx.x & 63;
    int row = blockIdx.x*4 + wave;                  // row = l*8+b
    const bf16* xp = Xf + (size_t)row*NIN + lane*16;
    u16x8 v0 = *(const u16x8*)(xp);
    u16x8 v1 = *(const u16x8*)(xp + 8);
    float a0=0.f, a1=0.f, a2=0.f;
    #pragma unroll
    for (int i=0;i<16;i++){
        float xv = bits2f(i<8 ? v0[i&7] : v1[i&7]);
        int k = lane*16 + i;
        a0 += xv*Wc[k*3+0];
        a1 += xv*Wc[k*3+1];
        a2 += xv*Wc[k*3+2];
    }
    #pragma unroll
    for (int off=32; off; off>>=1){
        a0 += __shfl_down(a0, off);
        a1 += __shfl_down(a1, off);
        a2 += __shfl_down(a2, off);
    }
    if (lane == 0){
        int l = row >> 3, b = row & 7;
        float* op = out + ((size_t)b*L_SEQ + l)*3;
        op[0] = a0 + bc[0];
        op[1] = a1 + bc[1];
        op[2] = a2 + bc[2];
    }
}

// ----------------------------------------------------------------
extern "C" void kernel_launch(void* const* d_in, const int* in_sizes, int n_in,
                              void* d_out, int out_size, void* d_ws, size_t ws_size,
                              hipStream_t stream){
    (void)in_sizes; (void)n_in; (void)out_size;
    const float* X    = (const float*)d_in[0];
    const float* W[4]  = {(const float*)d_in[1],(const float*)d_in[4],(const float*)d_in[7],(const float*)d_in[10]};
    const float* wc[4] = {(const float*)d_in[2],(const float*)d_in[5],(const float*)d_in[8],(const float*)d_in[11]};
    const float* bb[4] = {(const float*)d_in[3],(const float*)d_in[6],(const float*)d_in[9],(const float*)d_in[12]};
    const float* Wcls = (const float*)d_in[13];
    const float* bcls = (const float*)d_in[14];
    float* out = (float*)d_out;

    // workspace layout:
    //   xA    bf16[16384*1024]  @ 0           33,554,432
    //   xB    bf16[16384*1024]  @ 33554432    33,554,432
    //   dxT   f32 [8*2048]      @ 67108864        65,536
    //   carry f32 [8192]        @ 67174400        32,768
    //   Wt0-2 bf16[3072*1024]   @ 67207168    3 x 6,291,456
    //   Ucb   bf16[C*2*8*1536]  @ 86081536    C*49,152   (C=2048 -> 100MB)
    char*  ws    = (char*)d_ws;
    bf16*  xA    = (bf16*)ws;
    bf16*  xB    = (bf16*)(ws + 33554432);
    float* dxT   = (float*)(ws + 67108864);
    float* carry = (float*)(ws + 67174400);
    bf16*  Wt[3] = {(bf16*)(ws + 67207168), (bf16*)(ws + 73498624), (bf16*)(ws + 79790080)};
    bf16*  Ucb   = (bf16*)(ws + 86081536);
    const size_t NEEDED = 86081536ull + 64ull*49152ull;

    if (ws_size < NEEDED){
        float code = 1.0e6f + (float)((ws_size >> 20) > 9999 ? 9999 : (ws_size >> 20)) * 100.0f;
        k_code<<<1, 64, 0, stream>>>(out, code);
        return;
    }

    int C = 2048;
    while (C > 64 && 86081536ull + (size_t)C*49152ull > ws_size) C >>= 1;

    k_diff  <<<(NROWS+255)/256, 256, 0, stream>>>(X, dxT);
    for (int i = 0; i < 3; ++i)
        k_wt<<<dim3(32,96), 256, 0, stream>>>(W[i+1], Wt[i]);
    k_layer0<<<32, 256, 0, stream>>>(dxT, W[0], wc[0], bb[0], xA);

    bf16* xin = xA; bf16* xo = xB;
    for (int layer = 1; layer < 4; ++layer){
        for (int l0 = 0; l0 < L_SEQ; l0 += C){
            dim3 g(C*8/128, NHALF/128, 2);
            k_gemm<<<g, 256, 0, stream>>>(xin, Wt[layer-1], Ucb, l0, C);
            k_rec <<<32, 256, 0, stream>>>(Ucb, xin, xo, carry, wc[layer], bb[layer], l0, C);
        }
        bf16* t = xin; xin = xo; xo = t;
    }
    k_cls<<<NROWS/4, 256, 0, stream>>>(xin, Wcls, bcls, out);
}

// Round 19
// 1431.594 us; speedup vs baseline: 1.1623x; 1.0575x over previous
//
#include <hip/hip_runtime.h>
#include <hip/hip_bf16.h>

typedef __hip_bfloat16 bf16;
typedef unsigned short u16x8 __attribute__((ext_vector_type(8)));
using v8s = __attribute__((ext_vector_type(8))) short;   // bf16 x8 MFMA frag (4 VGPR)
using v4f = __attribute__((ext_vector_type(4))) float;   // f32 x4 acc frag

#define L_SEQ 2048
#define BATCH 8
#define NIN   1024    // 2H
#define WLD   3072    // W row stride, layers 1-3
#define NHALF 1536    // per-direction columns (3*H)
#define NROWS (L_SEQ*BATCH)

__device__ __forceinline__ float bits2f(unsigned short u){ return __uint_as_float(((unsigned)u)<<16); }
__device__ __forceinline__ float b2f(bf16 v){ return __bfloat162float(v); }
__device__ __forceinline__ bf16  f2b(float v){ return __float2bfloat16(v); }
__device__ __forceinline__ float sigm(float z){ return __fdividef(1.0f, 1.0f + __expf(-z)); }

__device__ __forceinline__ void gload16(const void* g, void* l){
    __builtin_amdgcn_global_load_lds((const __attribute__((address_space(1))) void*)g,
                                     (__attribute__((address_space(3))) void*)l, 16, 0, 0);
}

__global__ void k_code(float* __restrict__ out, float v){
    if (threadIdx.x == 0 && blockIdx.x == 0) out[0] = v;
}

// ---------------- dxT[b][l] = X[b][l] - X[b][l-1], 0 at l=0  ((B,L) layout)
__global__ __launch_bounds__(256) void k_diff(const float* __restrict__ X, float* __restrict__ dxT){
    int i = blockIdx.x*256 + threadIdx.x;
    if (i >= NROWS) return;
    int l = i & (L_SEQ-1);
    float v = 0.f;
    if (l > 0) v = X[i] - X[i-1];
    dxT[i] = v;
}

// ---------------- W (fp32 [1024][3072]) -> Wt (bf16 [3072][1024], transposed)
__global__ __launch_bounds__(256) void k_wt(const float* __restrict__ W, bf16* __restrict__ Wt){
    __shared__ float t[32][33];
    int k0 = blockIdx.x*32, n0 = blockIdx.y*32;
    int tx = threadIdx.x & 31, ty = threadIdx.x >> 5;   // ty 0..7
    #pragma unroll
    for (int j=0;j<4;j++)
        t[ty*4+j][tx] = W[(size_t)(k0+ty*4+j)*WLD + n0 + tx];
    __syncthreads();
    #pragma unroll
    for (int j=0;j<4;j++)
        Wt[(size_t)(n0+ty*4+j)*NIN + k0 + tx] = f2b(t[tx][ty*4+j]);
}

// ---------------- layer 0 (round-14 hoisted version, 201us measured)
__global__ __launch_bounds__(256) void k_layer0(const float* __restrict__ dxT, const float* __restrict__ W0,
                                                const float* __restrict__ wc, const float* __restrict__ bb,
                                                bf16* __restrict__ xout){
    __shared__ float sdx[L_SEQ];
    int g = blockIdx.x*256 + threadIdx.x;           // 8192 threads: (d,b,h); b,d block-uniform
    int h = g & 511, b = (g>>9) & 7, d = g >> 12;
    const float* dxp = dxT + b*L_SEQ;
    for (int t = threadIdx.x; t < L_SEQ; t += 256) sdx[t] = dxp[t];
    __syncthreads();

    int dcol = d*512 + h;
    float w0 = W0[d*2048 + h];
    float w1 = W0[d*2048 + 512 + h];
    float w2 = W0[d*2048 + 1024 + h];
    float w3 = W0[d*2048 + 1536 + h];
    float vf = wc[dcol],  vr = wc[1024 + dcol];
    float bfv = bb[dcol], brv = bb[1024 + dcol];
    float c = 0.f;

    int t0 = d ? (L_SEQ-1) : 0;
    bf16* xq = xout + ((size_t)t0*BATCH + b)*NIN + dcol;
    ptrdiff_t xs = d ? -(ptrdiff_t)(BATCH*NIN) : (ptrdiff_t)(BATCH*NIN);

#define LD0(P0,P1,P2,P3, s0) do{                                     \
        _Pragma("unroll")                                            \
        for (int i_=0;i_<8;i_++){                                    \
            int ss_ = (s0)+i_;                                       \
            float xv_ = sdx[d ? (L_SEQ-1-ss_) : ss_];                \
            P0[i_] = xv_*w0;                                         \
            P1[i_] = xv_*w1 + bfv;                                   \
            P2[i_] = xv_*w2 + brv;                                   \
            P3[i_] = xv_*w3;                                         \
        }                                                            \
        __builtin_amdgcn_sched_barrier(0);                           \
    }while(0)

#define STEP0(p0,p1,p2,p3) do{                                       \
        float f_ = sigm((p1) + vf*c);                                \
        c = (p0) + f_*(c - (p0));                                    \
        float r_ = sigm((p2) + vr*c);                                \
        float hv_ = (p3) + r_*(c - (p3));                            \
        *xq = f2b(hv_);  xq += xs;                                   \
    }while(0)

    float A0[8],A1[8],A2[8],A3[8], B0[8],B1[8],B2[8],B3[8];
    LD0(A0,A1,A2,A3, 0);
    for (int s0 = 0; s0 + 32 <= L_SEQ; s0 += 16){
        LD0(B0,B1,B2,B3, s0+8);
        #pragma unroll
        for (int i=0;i<8;i++) STEP0(A0[i],A1[i],A2[i],A3[i]);
        LD0(A0,A1,A2,A3, s0+16);
        #pragma unroll
        for (int i=0;i<8;i++) STEP0(B0[i],B1[i],B2[i],B3[i]);
    }
    LD0(B0,B1,B2,B3, L_SEQ-8);
    #pragma unroll
    for (int i=0;i<8;i++) STEP0(A0[i],A1[i],A2[i],A3[i]);
    #pragma unroll
    for (int i=0;i<8;i++) STEP0(B0[i],B1[i],B2[i],B3[i]);
#undef LD0
#undef STEP0
}

// ---------------- MFMA GEMM: UcH[set s] = x[all rows] @ Wt[set s]^T   (bf16 output)
// 128x128 tile, BK=32, 4 waves, triple-buffer dist-2, swizzle retained. (unchanged)
__global__ __launch_bounds__(256) void k_gemm(const bf16* __restrict__ Xin, const bf16* __restrict__ Wt,
                                              bf16* __restrict__ Uc, int l0, int C){
    __shared__ bf16 As[3][4096];   // [buf][128 m][32 k], 64B rows (8KB/buf)
    __shared__ bf16 Bs[3][4096];
    int tid = threadIdx.x;
    int lane = tid & 63;
    int s = blockIdx.z;
    int base = (s == 0) ? l0 : (L_SEQ - l0 - C);
    const bf16* A  = Xin + (size_t)base*BATCH*NIN;
    const bf16* Bm = Wt + (size_t)s*NHALF*NIN;
    bf16*       Cc = Uc + (size_t)s*(size_t)C*BATCH*NHALF;

    int m0 = blockIdx.x*128, n0 = blockIdx.y*128;
    int wv = tid >> 6;
    int wm = (wv >> 1)*64, wn = (wv & 1)*64;

    v4f acc[4][4];
    #pragma unroll
    for (int i=0;i<4;i++)
        #pragma unroll
        for (int j=0;j<4;j++)
            #pragma unroll
            for (int r=0;r<4;r++) acc[i][j][r] = 0.f;

    int row_a = tid >> 2;
    int kb = (((tid & 3) ^ ((tid >> 3) & 3)))*8;            // source-side swizzle
    int wbase = (tid & 192)*16;
    int fro = (lane & 15)*64 + (((lane >> 4) ^ (((lane & 15) >> 1) & 3)))*16;  // read-side swizzle

#define STAGE(q, k0) do{                                                        \
        char* la_ = (char*)As[0] + (q)*8192;                                    \
        char* lb_ = (char*)Bs[0] + (q)*8192;                                    \
        gload16(A  + (size_t)(m0 + row_a      )*NIN + (k0) + kb, la_ + wbase);  \
        gload16(A  + (size_t)(m0 + row_a + 64 )*NIN + (k0) + kb, la_ + 4096 + wbase); \
        gload16(Bm + (size_t)(n0 + row_a      )*NIN + (k0) + kb, lb_ + wbase);  \
        gload16(Bm + (size_t)(n0 + row_a + 64 )*NIN + (k0) + kb, lb_ + 4096 + wbase); \
    }while(0)

    STAGE(0, 0);
    STAGE(1, 32);
    int cur = 0;
    for (int it = 0; it < 32; ++it){
        if (it < 30){
            int nb = cur + 2; if (nb >= 3) nb -= 3;
            STAGE(nb, (it+2)*32);
            asm volatile("s_waitcnt vmcnt(8)" ::: "memory");   // drain tile-it (2 iters old)
        } else if (it == 30){
            asm volatile("s_waitcnt vmcnt(4)" ::: "memory");
        } else {
            asm volatile("s_waitcnt vmcnt(0)" ::: "memory");
        }
        __builtin_amdgcn_sched_barrier(0);
        __builtin_amdgcn_s_barrier();
        const char* la = (const char*)As[0] + cur*8192;
        const char* lb = (const char*)Bs[0] + cur*8192;
        v8s av[4], bv[4];
        #pragma unroll
        for (int i=0;i<4;i++) av[i] = *(const v8s*)(la + (wm + i*16)*64 + fro);
        #pragma unroll
        for (int j=0;j<4;j++) bv[j] = *(const v8s*)(lb + (wn + j*16)*64 + fro);
        #pragma unroll
        for (int i=0;i<4;i++)
            #pragma unroll
            for (int j=0;j<4;j++)
                acc[i][j] = __builtin_amdgcn_mfma_f32_16x16x32_bf16(av[i], bv[j], acc[i][j], 0, 0, 0);
        __builtin_amdgcn_s_barrier();
        cur = cur + 1; if (cur == 3) cur = 0;
    }
#undef STAGE

    int cr = (lane >> 4)*4, ccol = lane & 15;
    #pragma unroll
    for (int i=0;i<4;i++){
        #pragma unroll
        for (int j=0;j<4;j++){
            size_t rb = (size_t)(m0 + wm + i*16 + cr)*NHALF + (n0 + wn + j*16 + ccol);
            #pragma unroll
            for (int r=0;r<4;r++) Cc[rb + (size_t)r*NHALF] = f2b(acc[i][j][r]);
        }
    }
}

// ---------------- recurrence, layers 1-3: SINGLE-WAVE blocks, zero barriers.
// 128 blocks x 64 threads: block owns (d, b, 64-ch slice). 16-step groups, dbuf LDS 16KB.
// Per group: 6 U-gloads + 2 x-gloads (per-lane global addr, wave-uniform LDS dest).
// Counted vmcnt(24) steady / (16) tail — no s_barrier at all (1 wave).
__global__ __launch_bounds__(64) void k_rec(const bf16* __restrict__ Uc, const bf16* __restrict__ xin,
                                            bf16* __restrict__ xout, float* __restrict__ carry,
                                            const float* __restrict__ wc, const float* __restrict__ bb,
                                            int l0, int C){
    __shared__ bf16 Ub[2][3072];    // [buf][seg=step*3+gate][64 bf16]  2x6KB
    __shared__ bf16 Xb[2][1024];    // [buf][step][64 bf16]             2x2KB
    int tid = threadIdx.x;          // 0..63
    int bid = blockIdx.x;           // 0..127
    int d = bid >> 6, b = (bid >> 3) & 7, hbase = (bid & 7)*64;
    int h = hbase + tid;
    int dcol = d*512 + h;
    int ch = d*4096 + b*512 + h;
    float vf = wc[d*512 + h], vr = wc[1024 + d*512 + h];
    float bfv = bb[d*512 + h], brv = bb[1024 + d*512 + h];
    float c = (l0 == 0) ? 0.f : carry[ch];

    const bf16* Ubase = Uc + (size_t)d*(size_t)C*12288 + b*1536 + hbase;   // row stride 12288 bf16
    int lo3 = tid >> 3, ci8 = (tid & 7)*8;   // seg-sublane split: 8 lanes x 16B per 128B seg

#define RSTAGE(base_, q_) do{                                                   \
        char* ub_ = (char*)Ub[q_]; char* xb_ = (char*)Xb[q_];                   \
        _Pragma("unroll")                                                       \
        for (int qq=0; qq<6; ++qq){                                             \
            int seg = qq*8 + lo3;                   /* 0..47 */                 \
            int st_ = seg/3, gate_ = seg - st_*3;                               \
            int ss_ = (base_) + st_;                                            \
            int row_ = d ? (C-1-ss_) : ss_;                                     \
            gload16(Ubase + (size_t)row_*12288 + gate_*512 + ci8,               \
                    ub_ + qq*1024);                                             \
        }                                                                       \
        _Pragma("unroll")                                                       \
        for (int j=0;j<2;++j){                                                  \
            int st_ = (base_) + j*8 + lo3;                                      \
            int t_  = d ? (L_SEQ-1 - l0 - st_) : (l0 + st_);                    \
            gload16(xin + ((size_t)t_*BATCH + b)*NIN + d*512 + hbase + ci8,     \
                    xb_ + j*1024);                                              \
        }                                                                       \
    }while(0)

#define RCOMP(base_, q_) do{                                                    \
        float u0[16],u1[16],u2[16],xr[16];                                      \
        _Pragma("unroll")                                                       \
        for (int i_=0;i_<16;i_++){                                              \
            u0[i_]=b2f(Ub[q_][(i_*3+0)*64+tid]);                                \
            u1[i_]=b2f(Ub[q_][(i_*3+1)*64+tid]) + bfv;                          \
            u2[i_]=b2f(Ub[q_][(i_*3+2)*64+tid]) + brv;                          \
            xr[i_]=b2f(Xb[q_][i_*64+tid]);                                      \
        }                                                                       \
        __builtin_amdgcn_sched_barrier(0);                                      \
        _Pragma("unroll")                                                       \
        for (int i_=0;i_<16;i_++){                                              \
            int ss_=(base_)+i_;                                                 \
            int t_ = d ? (L_SEQ-1-l0-ss_) : (l0+ss_);                           \
            float f_=sigm(u1[i_] + vf*c);                                       \
            c = u0[i_] + f_*(c - u0[i_]);                                       \
            float r_=sigm(u2[i_] + vr*c);                                       \
            xout[((size_t)t_*BATCH + b)*NIN + dcol] = f2b(xr[i_] + r_*(c - xr[i_])); \
        }                                                                       \
    }while(0)

    RSTAGE(0, 0);
    asm volatile("s_waitcnt vmcnt(0)" ::: "memory");
    __builtin_amdgcn_sched_barrier(0);
    int ngrp = C >> 4;
    for (int g = 0; g < ngrp; ++g){
        int q = g & 1;
        if (g + 1 < ngrp){
            RSTAGE((g+1)*16, q^1);                           // queue: L(g)8 | S(g-1)16 | L(g+1)8
            asm volatile("s_waitcnt vmcnt(24)" ::: "memory");// drain exactly L(g)
        } else {
            asm volatile("s_waitcnt vmcnt(16)" ::: "memory");// queue: L(g)8 | S(g-1)16
        }
        __builtin_amdgcn_sched_barrier(0);
        RCOMP(g*16, q);
    }
    carry[ch] = c;
#undef RSTAGE
#undef RCOMP
}

// ---------------- classifier: out[(b*L + l)*3 + j] = h[row l*8+b] @ Wcls + bcls
__global__ __launch_bounds__(256) void k_cls(const bf16* __restrict__ Xf, const float* __restrict__ Wc,
                                             const float* __restrict__ bc, float* __restrict__ out){
    int wave = threadIdx.x >> 6, lane = threadIdx.x & 63;
    int row = blockIdx.x*4 + wave;                  // row = l*8+b
    const bf16* xp = Xf + (size_t)row*NIN + lane*16;
    u16x8 v0 = *(const u16x8*)(xp);
    u16x8 v1 = *(const u16x8*)(xp + 8);
    float a0=0.f, a1=0.f, a2=0.f;
    #pragma unroll
    for (int i=0;i<16;i++){
        float xv = bits2f(i<8 ? v0[i&7] : v1[i&7]);
        int k = lane*16 + i;
        a0 += xv*Wc[k*3+0];
        a1 += xv*Wc[k*3+1];
        a2 += xv*Wc[k*3+2];
    }
    #pragma unroll
    for (int off=32; off; off>>=1){
        a0 += __shfl_down(a0, off);
        a1 += __shfl_down(a1, off);
        a2 += __shfl_down(a2, off);
    }
    if (lane == 0){
        int l = row >> 3, b = row & 7;
        float* op = out + ((size_t)b*L_SEQ + l)*3;
        op[0] = a0 + bc[0];
        op[1] = a1 + bc[1];
        op[2] = a2 + bc[2];
    }
}

// ----------------------------------------------------------------
extern "C" void kernel_launch(void* const* d_in, const int* in_sizes, int n_in,
                              void* d_out, int out_size, void* d_ws, size_t ws_size,
                              hipStream_t stream){
    (void)in_sizes; (void)n_in; (void)out_size;
    const float* X    = (const float*)d_in[0];
    const float* W[4]  = {(const float*)d_in[1],(const float*)d_in[4],(const float*)d_in[7],(const float*)d_in[10]};
    const float* wc[4] = {(const float*)d_in[2],(const float*)d_in[5],(const float*)d_in[8],(const float*)d_in[11]};
    const float* bb[4] = {(const float*)d_in[3],(const float*)d_in[6],(const float*)d_in[9],(const float*)d_in[12]};
    const float* Wcls = (const float*)d_in[13];
    const float* bcls = (const float*)d_in[14];
    float* out = (float*)d_out;

    // workspace layout:
    //   xA    bf16[16384*1024]  @ 0           33,554,432
    //   xB    bf16[16384*1024]  @ 33554432    33,554,432
    //   dxT   f32 [8*2048]      @ 67108864        65,536
    //   carry f32 [8192]        @ 67174400        32,768
    //   Wt0-2 bf16[3072*1024]   @ 67207168    3 x 6,291,456
    //   Ucb   bf16[C*2*8*1536]  @ 86081536    C*49,152   (C=2048 -> 100MB)
    char*  ws    = (char*)d_ws;
    bf16*  xA    = (bf16*)ws;
    bf16*  xB    = (bf16*)(ws + 33554432);
    float* dxT   = (float*)(ws + 67108864);
    float* carry = (float*)(ws + 67174400);
    bf16*  Wt[3] = {(bf16*)(ws + 67207168), (bf16*)(ws + 73498624), (bf16*)(ws + 79790080)};
    bf16*  Ucb   = (bf16*)(ws + 86081536);
    const size_t NEEDED = 86081536ull + 64ull*49152ull;

    if (ws_size < NEEDED){
        float code = 1.0e6f + (float)((ws_size >> 20) > 9999 ? 9999 : (ws_size >> 20)) * 100.0f;
        k_code<<<1, 64, 0, stream>>>(out, code);
        return;
    }

    int C = 2048;
    while (C > 64 && 86081536ull + (size_t)C*49152ull > ws_size) C >>= 1;

    k_diff  <<<(NROWS+255)/256, 256, 0, stream>>>(X, dxT);
    for (int i = 0; i < 3; ++i)
        k_wt<<<dim3(32,96), 256, 0, stream>>>(W[i+1], Wt[i]);
    k_layer0<<<32, 256, 0, stream>>>(dxT, W[0], wc[0], bb[0], xA);

    bf16* xin = xA; bf16* xo = xB;
    for (int layer = 1; layer < 4; ++layer){
        for (int l0 = 0; l0 < L_SEQ; l0 += C){
            dim3 g(C*8/128, NHALF/128, 2);
            k_gemm<<<g, 256, 0, stream>>>(xin, Wt[layer-1], Ucb, l0, C);
            k_rec <<<128, 64, 0, stream>>>(Ucb, xin, xo, carry, wc[layer], bb[layer], l0, C);
        }
        bf16* t = xin; xin = xo; xo = t;
    }
    k_cls<<<NROWS/4, 256, 0, stream>>>(xin, Wcls, bcls, out);
}

// Round 20
// 1321.661 us; speedup vs baseline: 1.2590x; 1.0832x over previous
//
#include <hip/hip_runtime.h>
#include <hip/hip_bf16.h>

typedef __hip_bfloat16 bf16;
typedef unsigned short u16x8 __attribute__((ext_vector_type(8)));
using v8s = __attribute__((ext_vector_type(8))) short;   // bf16 x8 MFMA frag (4 VGPR)
using v4f = __attribute__((ext_vector_type(4))) float;   // f32 x4 acc frag

#define L_SEQ 2048
#define BATCH 8
#define NIN   1024    // 2H
#define WLD   3072    // W row stride, layers 1-3
#define NHALF 1536    // per-direction columns (3*H)
#define NROWS (L_SEQ*BATCH)
#define L2E   1.4426950408889634f

__device__ __forceinline__ float bits2f(unsigned short u){ return __uint_as_float(((unsigned)u)<<16); }
__device__ __forceinline__ float b2f(bf16 v){ return __bfloat162float(v); }
__device__ __forceinline__ bf16  f2b(float v){ return __float2bfloat16(v); }

__device__ __forceinline__ void gload16(const void* g, void* l){
    __builtin_amdgcn_global_load_lds((const __attribute__((address_space(1))) void*)g,
                                     (__attribute__((address_space(3))) void*)l, 16, 0, 0);
}

__global__ void k_code(float* __restrict__ out, float v){
    if (threadIdx.x == 0 && blockIdx.x == 0) out[0] = v;
}

// ---------------- dxT[b][l] = X[b][l] - X[b][l-1], 0 at l=0  ((B,L) layout)
__global__ __launch_bounds__(256) void k_diff(const float* __restrict__ X, float* __restrict__ dxT){
    int i = blockIdx.x*256 + threadIdx.x;
    if (i >= NROWS) return;
    int l = i & (L_SEQ-1);
    float v = 0.f;
    if (l > 0) v = X[i] - X[i-1];
    dxT[i] = v;
}

// ---------------- W (fp32 [1024][3072]) -> Wt (bf16 [3072][1024], transposed)
__global__ __launch_bounds__(256) void k_wt(const float* __restrict__ W, bf16* __restrict__ Wt){
    __shared__ float t[32][33];
    int k0 = blockIdx.x*32, n0 = blockIdx.y*32;
    int tx = threadIdx.x & 31, ty = threadIdx.x >> 5;   // ty 0..7
    #pragma unroll
    for (int j=0;j<4;j++)
        t[ty*4+j][tx] = W[(size_t)(k0+ty*4+j)*WLD + n0 + tx];
    __syncthreads();
    #pragma unroll
    for (int j=0;j<4;j++)
        Wt[(size_t)(n0+ty*4+j)*NIN + k0 + tx] = f2b(t[tx][ty*4+j]);
}

// ---------------- layer 0: chain/post split — only the f-gate sigmoid stays serial;
// r/h/store batched per 8 steps. log2e folded into gate pre-activations.
__global__ __launch_bounds__(256) void k_layer0(const float* __restrict__ dxT, const float* __restrict__ W0,
                                                const float* __restrict__ wc, const float* __restrict__ bb,
                                                bf16* __restrict__ xout){
    __shared__ float sdx[L_SEQ];
    int g = blockIdx.x*256 + threadIdx.x;           // 8192 threads: (d,b,h); b,d block-uniform
    int h = g & 511, b = (g>>9) & 7, d = g >> 12;
    const float* dxp = dxT + b*L_SEQ;
    for (int t = threadIdx.x; t < L_SEQ; t += 256) sdx[t] = dxp[t];
    __syncthreads();

    int dcol = d*512 + h;
    float w0  = W0[d*2048 + h];
    float w1L = W0[d*2048 + 512 + h]*L2E;
    float w2L = W0[d*2048 + 1024 + h]*L2E;
    float w3  = W0[d*2048 + 1536 + h];
    float vfL = wc[dcol]*L2E,  vrL = wc[1024 + dcol]*L2E;
    float bfvL = bb[dcol]*L2E, brvL = bb[1024 + dcol]*L2E;
    float c = 0.f;

    int t0 = d ? (L_SEQ-1) : 0;
    bf16* xq = xout + ((size_t)t0*BATCH + b)*NIN + dcol;
    ptrdiff_t xs = d ? -(ptrdiff_t)(BATCH*NIN) : (ptrdiff_t)(BATCH*NIN);

#define LD0(P0,P1,P2,P3, s0) do{                                     \
        _Pragma("unroll")                                            \
        for (int i_=0;i_<8;i_++){                                    \
            int ss_ = (s0)+i_;                                       \
            float xv_ = sdx[d ? (L_SEQ-1-ss_) : ss_];                \
            P0[i_] = xv_*w0;                                         \
            P1[i_] = fmaf(xv_, w1L, bfvL);                           \
            P2[i_] = fmaf(xv_, w2L, brvL);                           \
            P3[i_] = xv_*w3;                                         \
        }                                                            \
        __builtin_amdgcn_sched_barrier(0);                           \
    }while(0)

#define STEP8(P0,P1,P2,P3) do{                                       \
        float cs_[8];                                                \
        _Pragma("unroll")                                            \
        for (int i_=0;i_<8;i_++){                                    \
            float e_ = exp2f(fmaf(-vfL, c, -P1[i_]));                \
            float f_ = __builtin_amdgcn_rcpf(1.f + e_);              \
            c = fmaf(f_, c - P0[i_], P0[i_]);                        \
            cs_[i_] = c;                                             \
        }                                                            \
        __builtin_amdgcn_sched_barrier(0);                           \
        _Pragma("unroll")                                            \
        for (int i_=0;i_<8;i_++){                                    \
            float e2_ = exp2f(fmaf(-vrL, cs_[i_], -P2[i_]));         \
            float r_ = __builtin_amdgcn_rcpf(1.f + e2_);             \
            xq[(ptrdiff_t)i_*xs] = f2b(fmaf(r_, cs_[i_]-P3[i_], P3[i_])); \
        }                                                            \
        xq += 8*xs;                                                  \
        __builtin_amdgcn_sched_barrier(0);                           \
    }while(0)

    float A0[8],A1[8],A2[8],A3[8], B0[8],B1[8],B2[8],B3[8];
    LD0(A0,A1,A2,A3, 0);
    for (int s0 = 0; s0 + 32 <= L_SEQ; s0 += 16){
        LD0(B0,B1,B2,B3, s0+8);
        STEP8(A0,A1,A2,A3);
        LD0(A0,A1,A2,A3, s0+16);
        STEP8(B0,B1,B2,B3);
    }
    LD0(B0,B1,B2,B3, L_SEQ-8);
    STEP8(A0,A1,A2,A3);
    STEP8(B0,B1,B2,B3);
#undef LD0
#undef STEP8
}

// ---------------- MFMA GEMM: UcH[set s] = x[all rows] @ Wt[set s]^T   (bf16 output, unchanged)
__global__ __launch_bounds__(256) void k_gemm(const bf16* __restrict__ Xin, const bf16* __restrict__ Wt,
                                              bf16* __restrict__ Uc, int l0, int C){
    __shared__ bf16 As[3][4096];   // [buf][128 m][32 k], 64B rows (8KB/buf)
    __shared__ bf16 Bs[3][4096];
    int tid = threadIdx.x;
    int lane = tid & 63;
    int s = blockIdx.z;
    int base = (s == 0) ? l0 : (L_SEQ - l0 - C);
    const bf16* A  = Xin + (size_t)base*BATCH*NIN;
    const bf16* Bm = Wt + (size_t)s*NHALF*NIN;
    bf16*       Cc = Uc + (size_t)s*(size_t)C*BATCH*NHALF;

    int m0 = blockIdx.x*128, n0 = blockIdx.y*128;
    int wv = tid >> 6;
    int wm = (wv >> 1)*64, wn = (wv & 1)*64;

    v4f acc[4][4];
    #pragma unroll
    for (int i=0;i<4;i++)
        #pragma unroll
        for (int j=0;j<4;j++)
            #pragma unroll
            for (int r=0;r<4;r++) acc[i][j][r] = 0.f;

    int row_a = tid >> 2;
    int kb = (((tid & 3) ^ ((tid >> 3) & 3)))*8;            // source-side swizzle
    int wbase = (tid & 192)*16;
    int fro = (lane & 15)*64 + (((lane >> 4) ^ (((lane & 15) >> 1) & 3)))*16;  // read-side swizzle

#define STAGE(q, k0) do{                                                        \
        char* la_ = (char*)As[0] + (q)*8192;                                    \
        char* lb_ = (char*)Bs[0] + (q)*8192;                                    \
        gload16(A  + (size_t)(m0 + row_a      )*NIN + (k0) + kb, la_ + wbase);  \
        gload16(A  + (size_t)(m0 + row_a + 64 )*NIN + (k0) + kb, la_ + 4096 + wbase); \
        gload16(Bm + (size_t)(n0 + row_a      )*NIN + (k0) + kb, lb_ + wbase);  \
        gload16(Bm + (size_t)(n0 + row_a + 64 )*NIN + (k0) + kb, lb_ + 4096 + wbase); \
    }while(0)

    STAGE(0, 0);
    STAGE(1, 32);
    int cur = 0;
    for (int it = 0; it < 32; ++it){
        if (it < 30){
            int nb = cur + 2; if (nb >= 3) nb -= 3;
            STAGE(nb, (it+2)*32);
            asm volatile("s_waitcnt vmcnt(8)" ::: "memory");   // drain tile-it (2 iters old)
        } else if (it == 30){
            asm volatile("s_waitcnt vmcnt(4)" ::: "memory");
        } else {
            asm volatile("s_waitcnt vmcnt(0)" ::: "memory");
        }
        __builtin_amdgcn_sched_barrier(0);
        __builtin_amdgcn_s_barrier();
        const char* la = (const char*)As[0] + cur*8192;
        const char* lb = (const char*)Bs[0] + cur*8192;
        v8s av[4], bv[4];
        #pragma unroll
        for (int i=0;i<4;i++) av[i] = *(const v8s*)(la + (wm + i*16)*64 + fro);
        #pragma unroll
        for (int j=0;j<4;j++) bv[j] = *(const v8s*)(lb + (wn + j*16)*64 + fro);
        #pragma unroll
        for (int i=0;i<4;i++)
            #pragma unroll
            for (int j=0;j<4;j++)
                acc[i][j] = __builtin_amdgcn_mfma_f32_16x16x32_bf16(av[i], bv[j], acc[i][j], 0, 0, 0);
        __builtin_amdgcn_s_barrier();
        cur = cur + 1; if (cur == 3) cur = 0;
    }
#undef STAGE

    int cr = (lane >> 4)*4, ccol = lane & 15;
    #pragma unroll
    for (int i=0;i<4;i++){
        #pragma unroll
        for (int j=0;j<4;j++){
            size_t rb = (size_t)(m0 + wm + i*16 + cr)*NHALF + (n0 + wn + j*16 + ccol);
            #pragma unroll
            for (int r=0;r<4;r++) Cc[rb + (size_t)r*NHALF] = f2b(acc[i][j][r]);
        }
    }
}

// ---------------- recurrence, layers 1-3: single-wave blocks, zero barriers, 16-step groups.
// NEW: chain/post split — serial region = f-gate only (fma->exp2->add->rcp->fma);
// r-sigmoid + h + stores batched (independent given cs[]). log2e folded in batch.
__global__ __launch_bounds__(64) void k_rec(const bf16* __restrict__ Uc, const bf16* __restrict__ xin,
                                            bf16* __restrict__ xout, float* __restrict__ carry,
                                            const float* __restrict__ wc, const float* __restrict__ bb,
                                            int l0, int C){
    __shared__ bf16 Ub[2][3072];    // [buf][seg=step*3+gate][64 bf16]  2x6KB
    __shared__ bf16 Xb[2][1024];    // [buf][step][64 bf16]             2x2KB
    int tid = threadIdx.x;          // 0..63
    int bid = blockIdx.x;           // 0..127
    int d = bid >> 6, b = (bid >> 3) & 7, hbase = (bid & 7)*64;
    int h = hbase + tid;
    int dcol = d*512 + h;
    int ch = d*4096 + b*512 + h;
    float vfL = wc[d*512 + h]*L2E, vrL = wc[1024 + d*512 + h]*L2E;
    float bfvL = bb[d*512 + h]*L2E, brvL = bb[1024 + d*512 + h]*L2E;
    float c = (l0 == 0) ? 0.f : carry[ch];

    const bf16* Ubase = Uc + (size_t)d*(size_t)C*12288 + b*1536 + hbase;   // row stride 12288 bf16
    int lo3 = tid >> 3, ci8 = (tid & 7)*8;   // seg-sublane split: 8 lanes x 16B per 128B seg

#define RSTAGE(base_, q_) do{                                                   \
        char* ub_ = (char*)Ub[q_]; char* xb_ = (char*)Xb[q_];                   \
        _Pragma("unroll")                                                       \
        for (int qq=0; qq<6; ++qq){                                             \
            int seg = qq*8 + lo3;                   /* 0..47 */                 \
            int st_ = seg/3, gate_ = seg - st_*3;                               \
            int ss_ = (base_) + st_;                                            \
            int row_ = d ? (C-1-ss_) : ss_;                                     \
            gload16(Ubase + (size_t)row_*12288 + gate_*512 + ci8,               \
                    ub_ + qq*1024);                                             \
        }                                                                       \
        _Pragma("unroll")                                                       \
        for (int j=0;j<2;++j){                                                  \
            int st_ = (base_) + j*8 + lo3;                                      \
            int t_  = d ? (L_SEQ-1 - l0 - st_) : (l0 + st_);                    \
            gload16(xin + ((size_t)t_*BATCH + b)*NIN + d*512 + hbase + ci8,     \
                    xb_ + j*1024);                                              \
        }                                                                       \
    }while(0)

#define RCOMP(base_, q_) do{                                                    \
        float u0[16],u1L[16],u2L[16],xr[16],cs[16];                             \
        _Pragma("unroll")                                                       \
        for (int i_=0;i_<16;i_++){                                              \
            u0[i_] = b2f(Ub[q_][(i_*3+0)*64+tid]);                              \
            u1L[i_]= fmaf(b2f(Ub[q_][(i_*3+1)*64+tid]), L2E, bfvL);             \
            u2L[i_]= fmaf(b2f(Ub[q_][(i_*3+2)*64+tid]), L2E, brvL);             \
            xr[i_] = b2f(Xb[q_][i_*64+tid]);                                    \
        }                                                                       \
        __builtin_amdgcn_sched_barrier(0);                                      \
        _Pragma("unroll")                                                       \
        for (int i_=0;i_<16;i_++){                                              \
            float e_ = exp2f(fmaf(-vfL, c, -u1L[i_]));                          \
            float f_ = __builtin_amdgcn_rcpf(1.f + e_);                         \
            c = fmaf(f_, c - u0[i_], u0[i_]);                                   \
            cs[i_] = c;                                                         \
        }                                                                       \
        __builtin_amdgcn_sched_barrier(0);                                      \
        _Pragma("unroll")                                                       \
        for (int i_=0;i_<16;i_++){                                              \
            int ss_=(base_)+i_;                                                 \
            int t_ = d ? (L_SEQ-1-l0-ss_) : (l0+ss_);                           \
            float e2_ = exp2f(fmaf(-vrL, cs[i_], -u2L[i_]));                    \
            float r_ = __builtin_amdgcn_rcpf(1.f + e2_);                        \
            xout[((size_t)t_*BATCH + b)*NIN + dcol] = f2b(fmaf(r_, cs[i_]-xr[i_], xr[i_])); \
        }                                                                       \
    }while(0)

    RSTAGE(0, 0);
    asm volatile("s_waitcnt vmcnt(0)" ::: "memory");
    __builtin_amdgcn_sched_barrier(0);
    int ngrp = C >> 4;
    for (int g = 0; g < ngrp; ++g){
        int q = g & 1;
        if (g + 1 < ngrp){
            RSTAGE((g+1)*16, q^1);                           // queue: L(g)8 | S(g-1)16 | L(g+1)8
            asm volatile("s_waitcnt vmcnt(24)" ::: "memory");// drain exactly L(g)
        } else {
            asm volatile("s_waitcnt vmcnt(16)" ::: "memory");// queue: L(g)8 | S(g-1)16
        }
        __builtin_amdgcn_sched_barrier(0);
        RCOMP(g*16, q);
    }
    carry[ch] = c;
#undef RSTAGE
#undef RCOMP
}

// ---------------- classifier: out[(b*L + l)*3 + j] = h[row l*8+b] @ Wcls + bcls
__global__ __launch_bounds__(256) void k_cls(const bf16* __restrict__ Xf, const float* __restrict__ Wc,
                                             const float* __restrict__ bc, float* __restrict__ out){
    int wave = threadIdx.x >> 6, lane = threadIdx.x & 63;
    int row = blockIdx.x*4 + wave;                  // row = l*8+b
    const bf16* xp = Xf + (size_t)row*NIN + lane*16;
    u16x8 v0 = *(const u16x8*)(xp);
    u16x8 v1 = *(const u16x8*)(xp + 8);
    float a0=0.f, a1=0.f, a2=0.f;
    #pragma unroll
    for (int i=0;i<16;i++){
        float xv = bits2f(i<8 ? v0[i&7] : v1[i&7]);
        int k = lane*16 + i;
        a0 += xv*Wc[k*3+0];
        a1 += xv*Wc[k*3+1];
        a2 += xv*Wc[k*3+2];
    }
    #pragma unroll
    for (int off=32; off; off>>=1){
        a0 += __shfl_down(a0, off);
        a1 += __shfl_down(a1, off);
        a2 += __shfl_down(a2, off);
    }
    if (lane == 0){
        int l = row >> 3, b = row & 7;
        float* op = out + ((size_t)b*L_SEQ + l)*3;
        op[0] = a0 + bc[0];
        op[1] = a1 + bc[1];
        op[2] = a2 + bc[2];
    }
}

// ----------------------------------------------------------------
extern "C" void kernel_launch(void* const* d_in, const int* in_sizes, int n_in,
                              void* d_out, int out_size, void* d_ws, size_t ws_size,
                              hipStream_t stream){
    (void)in_sizes; (void)n_in; (void)out_size;
    const float* X    = (const float*)d_in[0];
    const float* W[4]  = {(const float*)d_in[1],(const float*)d_in[4],(const float*)d_in[7],(const float*)d_in[10]};
    const float* wc[4] = {(const float*)d_in[2],(const float*)d_in[5],(const float*)d_in[8],(const float*)d_in[11]};
    const float* bb[4] = {(const float*)d_in[3],(const float*)d_in[6],(const float*)d_in[9],(const float*)d_in[12]};
    const float* Wcls = (const float*)d_in[13];
    const float* bcls = (const float*)d_in[14];
    float* out = (float*)d_out;

    // workspace layout:
    //   xA    bf16[16384*1024]  @ 0           33,554,432
    //   xB    bf16[16384*1024]  @ 33554432    33,554,432
    //   dxT   f32 [8*2048]      @ 67108864        65,536
    //   carry f32 [8192]        @ 67174400        32,768
    //   Wt0-2 bf16[3072*1024]   @ 67207168    3 x 6,291,456
    //   Ucb   bf16[C*2*8*1536]  @ 86081536    C*49,152   (C=2048 -> 100MB)
    char*  ws    = (char*)d_ws;
    bf16*  xA    = (bf16*)ws;
    bf16*  xB    = (bf16*)(ws + 33554432);
    float* dxT   = (float*)(ws + 67108864);
    float* carry = (float*)(ws + 67174400);
    bf16*  Wt[3] = {(bf16*)(ws + 67207168), (bf16*)(ws + 73498624), (bf16*)(ws + 79790080)};
    bf16*  Ucb   = (bf16*)(ws + 86081536);
    const size_t NEEDED = 86081536ull + 64ull*49152ull;

    if (ws_size < NEEDED){
        float code = 1.0e6f + (float)((ws_size >> 20) > 9999 ? 9999 : (ws_size >> 20)) * 100.0f;
        k_code<<<1, 64, 0, stream>>>(out, code);
        return;
    }

    int C = 2048;
    while (C > 64 && 86081536ull + (size_t)C*49152ull > ws_size) C >>= 1;

    k_diff  <<<(NROWS+255)/256, 256, 0, stream>>>(X, dxT);
    for (int i = 0; i < 3; ++i)
        k_wt<<<dim3(32,96), 256, 0, stream>>>(W[i+1], Wt[i]);
    k_layer0<<<32, 256, 0, stream>>>(dxT, W[0], wc[0], bb[0], xA);

    bf16* xin = xA; bf16* xo = xB;
    for (int layer = 1; layer < 4; ++layer){
        for (int l0 = 0; l0 < L_SEQ; l0 += C){
            dim3 g(C*8/128, NHALF/128, 2);
            k_gemm<<<g, 256, 0, stream>>>(xin, Wt[layer-1], Ucb, l0, C);
            k_rec <<<128, 64, 0, stream>>>(Ucb, xin, xo, carry, wc[layer], bb[layer], l0, C);
        }
        bf16* t = xin; xin = xo; xo = t;
    }
    k_cls<<<NROWS/4, 256, 0, stream>>>(xin, Wcls, bcls, out);
}